// Round 6
// baseline (1462.497 us; speedup 1.0000x reference)
//
#include <hip/hip_runtime.h>
#include <stdint.h>

#define BATCH 4096
#define FEAT  40960
#define H1    512
#define KS    4
#define KCHUNK (FEAT / KS)    // 10240
#define NSTEPS (KCHUNK / 32)  // 320
#define NTILES (FEAT / 32)    // 1280
#define WTILE  32768          // bytes per pre-swizzled W k-tile (512 rows x 32 bf16)

typedef float f32x4 __attribute__((ext_vector_type(4)));
typedef short s16x8 __attribute__((ext_vector_type(8)));
typedef unsigned int u32x2 __attribute__((ext_vector_type(2)));
typedef unsigned int u32x4 __attribute__((ext_vector_type(4)));

// round-to-nearest-even f32 -> bf16, packed pair (lo in low 16 bits)
__device__ __forceinline__ unsigned bfpack2(float lo, float hi) {
  unsigned a = __float_as_uint(lo);
  unsigned b = __float_as_uint(hi);
  a += 0x7FFFu + ((a >> 16) & 1u);
  b += 0x7FFFu + ((b >> 16) & 1u);
  return (a >> 16) | (b & 0xFFFF0000u);
}

// HW packed f32->bf16 (RTNE): dst.lo16 = cvt(lo), dst.hi16 = cvt(hi)
__device__ __forceinline__ unsigned cvtpk(float lo, float hi) {
  unsigned r;
  asm("v_cvt_pk_bf16_f32 %0, %1, %2" : "=v"(r) : "v"(lo), "v"(hi));
  return r;
}

// Swizzle for 64B-row LDS tiles, 16B chunk granularity: chunk ^= (r>>1)&3.
// 16-lane fragment reads (rows R..R+15, fixed chunk) hit all 8 bank-quads
// exactly twice -> 2-way (free, m136). Bijective; preserves 8B alignment.
__device__ __forceinline__ int lds_swz(int r, int cb) {
  return (r << 6) + (cb ^ (((r >> 1) & 3) << 4));
}

// async global->LDS, 16B per lane; LDS dest = wave-uniform base + lane*16.
__device__ __forceinline__ void glds16(const void* g, void* l) {
  __builtin_amdgcn_global_load_lds(
      (const __attribute__((address_space(1))) unsigned*)g,
      (__attribute__((address_space(3))) unsigned*)l, 16, 0, 0);
}

// ---------------------------------------------------------------------------
// Kernel 0: one-time ftw f32 -> bf16, stored as 1280 ready-made 32KB LDS tile
// images (pre-swizzled source for global_load_lds, rule #21).
// ---------------------------------------------------------------------------
__global__ __launch_bounds__(512)
void wcvt_kernel(const float* __restrict__ ftw, char* __restrict__ wbf) {
  const int bid = blockIdx.x;  // NTILES*4
  const int T = bid >> 2, rq = bid & 3;
  const int tid = threadIdx.x;
  const int r = rq * 128 + (tid >> 2), kq = tid & 3;
  const float* src = ftw + (size_t)r * FEAT + T * 32 + kq * 8;
  f32x4 v0 = *(const f32x4*)src;
  f32x4 v1 = *(const f32x4*)(src + 4);
  u32x4 o;
  o.x = bfpack2(v0.x, v0.y); o.y = bfpack2(v0.z, v0.w);
  o.z = bfpack2(v1.x, v1.y); o.w = bfpack2(v1.z, v1.w);
  *(u32x4*)(wbf + (size_t)T * WTILE + lds_swz(r, kq * 16)) = o;
}

// ---------------------------------------------------------------------------
// Kernel 1: feature-transform GEMM, split-K partials. BARRIER-FREE.
// BM=64 BN=512 BK=32, 512 thr = 8 waves (1M x 8N), wave tile 64x64.
// Each wave is self-contained: it DMAs its own 4KB W slice (disjoint LDS
// region it alone reads -> per-wave vmcnt sync, no s_barrier) and loads its
// A fragments directly from global (8KB tile; 8x redundant reads are L1/L2
// hits; per-lrow lane quads form contiguous 128B segments -> coalesced).
// LDS 64KB (2 x 32KB W) -> 2 blocks/CU; 16 independent waves/CU hide latency.
// ---------------------------------------------------------------------------
__global__ __launch_bounds__(512, 4)
void ft_gemm_kernel(const float* __restrict__ whiteF,
                    const float* __restrict__ blackF,
                    const char* __restrict__ wbf,
                    float* __restrict__ Ppart) {
  __shared__ char smem[65536];

  const int tid = threadIdx.x, bid = blockIdx.x;
  const int wgid = (bid & 7) * 64 + (bid >> 3);  // XCD-chunked, bijective
  const int ks = wgid >> 7;         // 0..3
  const int p  = (wgid >> 6) & 1;   // perspective
  const int mt = wgid & 63;         // m-tile (64 rows)

  const float* Ag =
      (p == 0 ? whiteF : blackF) + (size_t)(mt * 64) * FEAT + ks * KCHUNK;

  const int lane = tid & 63, wave = tid >> 6;
  const int lrow = lane & 15, lkb = (lane >> 4) * 16;

  // A direct-fragment pointers: frag m, lane l -> row m*16+lrow, k (l>>4)*8
  const float* am[4];
#pragma unroll
  for (int m = 0; m < 4; ++m)
    am[m] = Ag + (size_t)(m * 16 + lrow) * FEAT + (lane >> 4) * 8;

  // W: per-wave slice of pre-swizzled tile image
  const char* wsrc = wbf + (size_t)ks * NSTEPS * WTILE + wave * 4096 + lane * 16;
  const int wdst = wave * 4096;

  const int wn = wave;
  int b_off[4];
#pragma unroll
  for (int n = 0; n < 4; ++n) b_off[n] = lds_swz(wn * 64 + n * 16 + lrow, lkb);

  f32x4 acc[4][4];
#pragma unroll
  for (int m = 0; m < 4; ++m)
#pragma unroll
    for (int n = 0; n < 4; ++n) acc[m][n] = (f32x4){0.f, 0.f, 0.f, 0.f};

  f32x4 raf[4][2];  // A(t) f32 staging (single-buffered; freed by cvt)

  // prologue: W(0) DMA -> buf0, A(0) loads. Queue invariant: [W(t):4, A(t):8]
#pragma unroll
  for (int c = 0; c < 4; ++c) glds16(wsrc + c * 1024, smem + wdst + c * 1024);
#pragma unroll
  for (int m = 0; m < 4; ++m) {
    raf[m][0] = *(const f32x4*)am[m];
    raf[m][1] = *(const f32x4*)(am[m] + 4);
  }

#define GSTEP(B, LAST, t)                                                     \
  {                                                                           \
    asm volatile("s_waitcnt lgkmcnt(0)" ::: "memory"); /* WAR: buf^1 reads */ \
    __builtin_amdgcn_sched_barrier(0);                                        \
    if (!(LAST)) {                                                            \
      const char* wsp = wsrc + (size_t)((t) + 1) * WTILE;                     \
      char* wdp = smem + ((B) ^ 1) * 32768 + wdst;                            \
      _Pragma("unroll") for (int c = 0; c < 4; ++c)                           \
          glds16(wsp + c * 1024, wdp + c * 1024);                             \
    }                                                                         \
    __builtin_amdgcn_sched_barrier(0);                                        \
    if (LAST) { asm volatile("s_waitcnt vmcnt(0)" ::: "memory"); }            \
    else      { asm volatile("s_waitcnt vmcnt(4)" ::: "memory"); }            \
    __builtin_amdgcn_sched_barrier(0);                                        \
    s16x8 af[4];                                                              \
    _Pragma("unroll") for (int m = 0; m < 4; ++m) {                           \
      u32x4 cv;                                                               \
      cv.x = cvtpk(raf[m][0].x, raf[m][0].y);                                 \
      cv.y = cvtpk(raf[m][0].z, raf[m][0].w);                                 \
      cv.z = cvtpk(raf[m][1].x, raf[m][1].y);                                 \
      cv.w = cvtpk(raf[m][1].z, raf[m][1].w);                                 \
      af[m] = __builtin_bit_cast(s16x8, cv);                                  \
    }                                                                         \
    if (!(LAST)) {                                                            \
      _Pragma("unroll") for (int m = 0; m < 4; ++m) {                         \
        const float* ap = am[m] + (size_t)((t) + 1) * 32;                     \
        raf[m][0] = *(const f32x4*)ap;                                        \
        raf[m][1] = *(const f32x4*)(ap + 4);                                  \
      }                                                                       \
    }                                                                         \
    const char* base = smem + (B) * 32768;                                    \
    _Pragma("unroll") for (int n = 0; n < 4; ++n) {                           \
      s16x8 bfn = *(const s16x8*)(base + b_off[n]);                           \
      _Pragma("unroll") for (int m = 0; m < 4; ++m)                           \
          acc[m][n] = __builtin_amdgcn_mfma_f32_16x16x32_bf16(                \
              af[m], bfn, acc[m][n], 0, 0, 0);                                \
    }                                                                         \
  }

  for (int tt = 0; tt < NSTEPS - 2; tt += 2) {
    GSTEP(0, false, tt);
    GSTEP(1, false, tt + 1);
  }
  GSTEP(0, false, NSTEPS - 2);
  GSTEP(1, true, NSTEPS - 1);
#undef GSTEP

  // C/D frag: col = lane&15, row = (lane>>4)*4 + j
  float* Pp = Ppart + ((size_t)(ks * 2 + p) * BATCH + mt * 64) * H1;
  const int r0 = (lane >> 4) * 4;
  const int c0 = wn * 64 + lrow;
#pragma unroll
  for (int m = 0; m < 4; ++m)
#pragma unroll
    for (int n = 0; n < 4; ++n) {
      float* dst = Pp + (size_t)(r0 + m * 16) * H1 + c0 + n * 16;
#pragma unroll
      for (int j = 0; j < 4; ++j) dst[(size_t)j * H1] = acc[m][n][j];
    }
}

// ---------------------------------------------------------------------------
// Kernel 2: reduce split-K partials + bias + clip[0,1] -> combined bf16
// ---------------------------------------------------------------------------
__global__ __launch_bounds__(256)
void ft_reduce_kernel(const float* __restrict__ Ppart,
                      const float* __restrict__ ftb,
                      unsigned short* __restrict__ comb) {
  const size_t gid = (size_t)blockIdx.x * 256 + threadIdx.x;  // 2*B*H1/4
  const int    pp  = (int)(gid / (BATCH * H1 / 4));
  const size_t rem = gid % (BATCH * H1 / 4);
  const int    row = (int)(rem / (H1 / 4));
  const int    n4  = (int)(rem % (H1 / 4)) * 4;

  f32x4 s = (f32x4){0.f, 0.f, 0.f, 0.f};
#pragma unroll
  for (int ks = 0; ks < KS; ++ks)
    s += *(const f32x4*)(Ppart + ((size_t)(ks * 2 + pp) * BATCH + row) * H1 + n4);
  const f32x4 bv = *(const f32x4*)(ftb + n4);
  s += bv;
  s.x = fminf(fmaxf(s.x, 0.f), 1.f);
  s.y = fminf(fmaxf(s.y, 0.f), 1.f);
  s.z = fminf(fmaxf(s.z, 0.f), 1.f);
  s.w = fminf(fmaxf(s.w, 0.f), 1.f);

  u32x2 o;
  o.x = bfpack2(s.x, s.y);
  o.y = bfpack2(s.z, s.w);
  *(u32x2*)(comb + (size_t)row * 1024 + pp * H1 + n4) = o;
}

// ---------------------------------------------------------------------------
// Kernel 3: fc1 (bf16 MFMA) + relu + fc2 dot + bias -> out FLOAT32 [4096]
// ---------------------------------------------------------------------------
__global__ __launch_bounds__(256)
void fc_kernel(const unsigned short* __restrict__ comb,
               const float* __restrict__ w1, const float* __restrict__ b1,
               const float* __restrict__ w2, const float* __restrict__ b2,
               float* __restrict__ out) {
  __shared__ char smem[40960];  // 2 x (A 4KB + W 16KB)
  __shared__ float rowsum[64];

  const int tid = threadIdx.x;
  const int bm  = blockIdx.x;  // 64 blocks of 64 rows
  if (tid < 64) rowsum[tid] = 0.f;

  const int a_row = tid >> 2, a_kq = tid & 3;
  const unsigned short* aptr = comb + (size_t)(bm * 64 + a_row) * 1024 + a_kq * 8;
  const float* wptr = w1 + (size_t)a_row * 1024 + a_kq * 8;

  u32x4 raA;
  f32x4 rw0[4], rw1[4];
  auto issue = [&](int t) {
    raA = *(const u32x4*)(aptr + t * 32);
    const float* wp = wptr + t * 32;
#pragma unroll
    for (int s = 0; s < 4; ++s) {
      rw0[s] = *(const f32x4*)(wp + (size_t)s * 64 * 1024);
      rw1[s] = *(const f32x4*)(wp + (size_t)s * 64 * 1024 + 4);
    }
  };

  const int aoff_w = lds_swz(a_row, a_kq * 16);
  int woff_w[4];
#pragma unroll
  for (int s = 0; s < 4; ++s)
    woff_w[s] = 4096 + lds_swz(s * 64 + a_row, a_kq * 16);

  auto cvtwrite = [&](int b) {
    char* base = smem + b * 20480;
    *(u32x4*)(base + aoff_w) = raA;
#pragma unroll
    for (int s = 0; s < 4; ++s) {
      u32x4 wv;
      wv.x = bfpack2(rw0[s].x, rw0[s].y); wv.y = bfpack2(rw0[s].z, rw0[s].w);
      wv.z = bfpack2(rw1[s].x, rw1[s].y); wv.w = bfpack2(rw1[s].z, rw1[s].w);
      *(u32x4*)(base + woff_w[s]) = wv;
    }
  };

  const int lane = tid & 63, wn = tid >> 6;
  const int lrow = lane & 15, lkb = (lane >> 4) * 16;
  int a_off[4], b_off[4];
#pragma unroll
  for (int m = 0; m < 4; ++m) a_off[m] = lds_swz(m * 16 + lrow, lkb);
#pragma unroll
  for (int n = 0; n < 4; ++n) b_off[n] = 4096 + lds_swz(wn * 64 + n * 16 + lrow, lkb);

  f32x4 acc[4][4];
#pragma unroll
  for (int m = 0; m < 4; ++m)
#pragma unroll
    for (int n = 0; n < 4; ++n) acc[m][n] = (f32x4){0.f, 0.f, 0.f, 0.f};

  issue(0);
  for (int t = 0; t < 32; ++t) {
    const int b = t & 1;
    cvtwrite(b);
    if (t + 1 < 32) issue(t + 1);
    asm volatile("s_waitcnt lgkmcnt(0)" ::: "memory");
    __builtin_amdgcn_sched_barrier(0);
    __builtin_amdgcn_s_barrier();
    __builtin_amdgcn_sched_barrier(0);
    char* base = smem + b * 20480;
    s16x8 af[4];
#pragma unroll
    for (int m = 0; m < 4; ++m) af[m] = *(const s16x8*)(base + a_off[m]);
#pragma unroll
    for (int n = 0; n < 4; ++n) {
      s16x8 bfn = *(const s16x8*)(base + b_off[n]);
#pragma unroll
      for (int m = 0; m < 4; ++m)
        acc[m][n] = __builtin_amdgcn_mfma_f32_16x16x32_bf16(af[m], bfn, acc[m][n], 0, 0, 0);
    }
  }

  float b1v[4], w2v[4];
#pragma unroll
  for (int n = 0; n < 4; ++n) {
    const int col = wn * 64 + n * 16 + lrow;
    b1v[n] = b1[col];
    w2v[n] = w2[col];
  }
#pragma unroll
  for (int m = 0; m < 4; ++m)
#pragma unroll
    for (int j = 0; j < 4; ++j) {
      float v = 0.f;
#pragma unroll
      for (int n = 0; n < 4; ++n) {
        float x = acc[m][n][j] + b1v[n];
        x = fmaxf(x, 0.f);
        v += x * w2v[n];
      }
#pragma unroll
      for (int d = 1; d < 16; d <<= 1) v += __shfl_xor(v, d, 64);
      if ((lane & 15) == 0)
        atomicAdd(&rowsum[m * 16 + (lane >> 4) * 4 + j], v);
    }
  __syncthreads();
  if (tid < 64) {
    out[bm * 64 + tid] = rowsum[tid] + b2[0];  // f32 output
  }
}

// ---------------------------------------------------------------------------
extern "C" void kernel_launch(void* const* d_in, const int* in_sizes, int n_in,
                              void* d_out, int out_size, void* d_ws, size_t ws_size,
                              hipStream_t stream) {
  const float* whiteF = (const float*)d_in[0];
  const float* blackF = (const float*)d_in[1];
  const float* ftw    = (const float*)d_in[2];
  const float* ftb    = (const float*)d_in[3];
  const float* w1     = (const float*)d_in[4];
  const float* b1     = (const float*)d_in[5];
  const float* w2     = (const float*)d_in[6];
  const float* b2     = (const float*)d_in[7];

  char* wbf = (char*)d_ws;                                   // 41,943,040 B
  const size_t wbf_bytes   = (size_t)NTILES * WTILE;
  const size_t ppart_bytes = (size_t)KS * 2 * BATCH * H1 * sizeof(float);
  float* Ppart = (float*)((char*)d_ws + wbf_bytes);
  unsigned short* comb = (unsigned short*)((char*)d_ws + wbf_bytes + ppart_bytes);
  float* outp = (float*)d_out;

  hipLaunchKernelGGL(wcvt_kernel, dim3(NTILES * 4), dim3(512), 0, stream, ftw, wbf);
  hipLaunchKernelGGL(ft_gemm_kernel, dim3(512), dim3(512), 0, stream,
                     whiteF, blackF, wbf, Ppart);
  hipLaunchKernelGGL(ft_reduce_kernel, dim3((2 * BATCH * H1 / 4) / 256), dim3(256),
                     0, stream, Ppart, ftb, comb);
  hipLaunchKernelGGL(fc_kernel, dim3(BATCH / 64), dim3(256), 0, stream,
                     comb, w1, b1, w2, b2, outp);
}

// Round 7
// 553.627 us; speedup vs baseline: 2.6417x; 2.6417x over previous
//
#include <hip/hip_runtime.h>
#include <stdint.h>

#define BATCH 4096
#define FEAT  40960
#define H1    512
#define KS    4
#define KCHUNK (FEAT / KS)    // 10240
#define NSTEPS (KCHUNK / 32)  // 320
#define NTILES (FEAT / 32)    // 1280
#define WTILE  32768          // bytes per fragment-major W k-tile

typedef float f32x4 __attribute__((ext_vector_type(4)));
typedef short s16x8 __attribute__((ext_vector_type(8)));
typedef unsigned int u32x2 __attribute__((ext_vector_type(2)));
typedef unsigned int u32x4 __attribute__((ext_vector_type(4)));

// round-to-nearest-even f32 -> bf16, packed pair (lo in low 16 bits)
__device__ __forceinline__ unsigned bfpack2(float lo, float hi) {
  unsigned a = __float_as_uint(lo);
  unsigned b = __float_as_uint(hi);
  a += 0x7FFFu + ((a >> 16) & 1u);
  b += 0x7FFFu + ((b >> 16) & 1u);
  return (a >> 16) | (b & 0xFFFF0000u);
}

// Swizzle for 64B-row LDS tiles (A staging), 16B granularity; 2-way = free.
__device__ __forceinline__ int lds_swz(int r, int cb) {
  return (r << 6) + (cb ^ (((r >> 1) & 3) << 4));
}

// ---------------------------------------------------------------------------
// Kernel 0: one-time ftw f32 -> bf16 in FRAGMENT-MAJOR order:
// wbf[T][nb][f][lane][8 bf16] = bf16(ftw[nb*64 + f*16 + (lane&15)]
//                                    [T*32 + (lane>>4)*8 .. +8])
// so a wave's MFMA B-fragment (frag f) is one contiguous 1KB chunk.
// Reads coalesced (consecutive tids -> consecutive k), writes scattered 8B.
// ---------------------------------------------------------------------------
__global__ __launch_bounds__(512)
void wcvt_kernel(const float* __restrict__ ftw, char* __restrict__ wbf) {
  const int T = blockIdx.x;  // 0..NTILES-1
  const int tid = threadIdx.x;
  const int c  = tid & 7;    // 4-f32 chunk within the 32-k row
  const int r0 = tid >> 3;   // 64 rows per pass
#pragma unroll
  for (int pass = 0; pass < 8; ++pass) {
    const int r = pass * 64 + r0;
    const float* src = ftw + (size_t)r * FEAT + T * 32 + c * 4;
    f32x4 v = *(const f32x4*)src;
    u32x2 o;
    o.x = bfpack2(v.x, v.y);
    o.y = bfpack2(v.z, v.w);
    const int nb = r >> 6, f = (r >> 4) & 3, lr = r & 15;
    const int l = (c >> 1) * 16 + lr;  // owning lane
    *(u32x2*)(wbf + (size_t)T * WTILE + ((nb * 4 + f) << 10) + l * 16 +
              (c & 1) * 8) = o;
  }
}

// ---------------------------------------------------------------------------
// Kernel 1: feature-transform GEMM, split-K partials.
// BM=64 BN=512 BK=32, 512 thr = 8 waves (1M x 8N), wave tile 64x64.
// A: cooperatively staged (read ONCE, coalesced) via 4KB LDS double-buffer —
//    the only barrier-coupled resource (lgkmcnt-only barrier, no vmcnt drain).
// W: per-wave register double-buffer, loaded as 4 contiguous 1KB fragment
//    chunks from the fragment-major image (L3-resident); compiler inserts
//    counted vmcnt for the register deps -> W latency spans a full step.
// LDS 8KB; VGPR ~126 -> 2 blocks/CU, 16 waves/CU.
// ---------------------------------------------------------------------------
__global__ __launch_bounds__(512, 4)
void ft_gemm_kernel(const float* __restrict__ whiteF,
                    const float* __restrict__ blackF,
                    const char* __restrict__ wbf,
                    float* __restrict__ Ppart) {
  __shared__ char smem[8192];  // 2 x 4KB A tiles

  const int tid = threadIdx.x, bid = blockIdx.x;
  const int wgid = (bid & 7) * 64 + (bid >> 3);  // XCD-chunked, bijective
  const int ks = wgid >> 7;         // 0..3
  const int p  = (wgid >> 6) & 1;   // perspective
  const int mt = wgid & 63;         // m-tile (64 rows)

  const float* Ag =
      (p == 0 ? whiteF : blackF) + (size_t)(mt * 64) * FEAT + ks * KCHUNK;

  // A staging: 64 rows x 8 threads/row x 4 f32 (coalesced 128B per row-quad)
  const int a_row = tid >> 3, a_kc = tid & 7;
  const float* aptr = Ag + (size_t)a_row * FEAT + a_kc * 4;
  const int awoff = lds_swz(a_row, a_kc * 8);

  const int lane = tid & 63, wave = tid >> 6;
  const int lrow = lane & 15, lkb = (lane >> 4) * 16;

  // W fragment source: wave's slice of fragment-major tile image
  const char* wsrc =
      wbf + (size_t)ks * NSTEPS * WTILE + (wave << 12) + lane * 16;

  int a_off[4];
#pragma unroll
  for (int m = 0; m < 4; ++m) a_off[m] = lds_swz(m * 16 + lrow, lkb);

  f32x4 acc[4][4];
#pragma unroll
  for (int m = 0; m < 4; ++m)
#pragma unroll
    for (int n = 0; n < 4; ++n) acc[m][n] = (f32x4){0.f, 0.f, 0.f, 0.f};

  f32x4 raA;        // A(t) f32 staging (single-buffered; reloaded after cvt)
  u32x4 rb[2][4];   // W fragment double-buffer

  // prologue: A(0), B(0)
  raA = *(const f32x4*)aptr;
#pragma unroll
  for (int n = 0; n < 4; ++n)
    rb[0][n] = *(const u32x4*)(wsrc + (n << 10));

#define GSTEP(B, LAST, t)                                                     \
  {                                                                           \
    /* cvt A(t) (auto vmcnt for raA) and stage to LDS buf B */                \
    u32x2 av;                                                                 \
    av.x = bfpack2(raA.x, raA.y);                                             \
    av.y = bfpack2(raA.z, raA.w);                                             \
    *(u32x2*)(smem + (B) * 4096 + awoff) = av;                                \
    if (!(LAST)) { /* issue A(t+1) into same regs (WAR ok: cvt consumed) */   \
      raA = *(const f32x4*)(aptr + (size_t)((t) + 1) * 32);                   \
      /* issue B(t+1) fragment loads */                                       \
      const char* wsp = wsrc + (size_t)((t) + 1) * WTILE;                     \
      _Pragma("unroll") for (int n = 0; n < 4; ++n)                           \
          rb[(B) ^ 1][n] = *(const u32x4*)(wsp + (n << 10));                  \
    }                                                                         \
    asm volatile("s_waitcnt lgkmcnt(0)" ::: "memory"); /* A write visible */  \
    __builtin_amdgcn_sched_barrier(0);                                        \
    __builtin_amdgcn_s_barrier();                                             \
    __builtin_amdgcn_sched_barrier(0);                                        \
    const char* base = smem + (B) * 4096;                                     \
    s16x8 af[4];                                                              \
    _Pragma("unroll") for (int m = 0; m < 4; ++m)                             \
        af[m] = *(const s16x8*)(base + a_off[m]);                             \
    _Pragma("unroll") for (int n = 0; n < 4; ++n) {                           \
      s16x8 bfn = __builtin_bit_cast(s16x8, rb[B][n]);                        \
      _Pragma("unroll") for (int m = 0; m < 4; ++m)                           \
          acc[m][n] = __builtin_amdgcn_mfma_f32_16x16x32_bf16(                \
              af[m], bfn, acc[m][n], 0, 0, 0);                                \
    }                                                                         \
  }

  for (int tt = 0; tt < NSTEPS - 2; tt += 2) {
    GSTEP(0, false, tt);
    GSTEP(1, false, tt + 1);
  }
  GSTEP(0, false, NSTEPS - 2);
  GSTEP(1, true, NSTEPS - 1);
#undef GSTEP

  // C/D frag: col = lane&15, row = (lane>>4)*4 + j
  float* Pp = Ppart + ((size_t)(ks * 2 + p) * BATCH + mt * 64) * H1;
  const int r0 = (lane >> 4) * 4;
  const int c0 = wave * 64 + lrow;
#pragma unroll
  for (int m = 0; m < 4; ++m)
#pragma unroll
    for (int n = 0; n < 4; ++n) {
      float* dst = Pp + (size_t)(r0 + m * 16) * H1 + c0 + n * 16;
#pragma unroll
      for (int j = 0; j < 4; ++j) dst[(size_t)j * H1] = acc[m][n][j];
    }
}

// ---------------------------------------------------------------------------
// Kernel 2: reduce split-K partials + bias + clip[0,1] -> combined bf16
// ---------------------------------------------------------------------------
__global__ __launch_bounds__(256)
void ft_reduce_kernel(const float* __restrict__ Ppart,
                      const float* __restrict__ ftb,
                      unsigned short* __restrict__ comb) {
  const size_t gid = (size_t)blockIdx.x * 256 + threadIdx.x;  // 2*B*H1/4
  const int    pp  = (int)(gid / (BATCH * H1 / 4));
  const size_t rem = gid % (BATCH * H1 / 4);
  const int    row = (int)(rem / (H1 / 4));
  const int    n4  = (int)(rem % (H1 / 4)) * 4;

  f32x4 s = (f32x4){0.f, 0.f, 0.f, 0.f};
#pragma unroll
  for (int ks = 0; ks < KS; ++ks)
    s += *(const f32x4*)(Ppart + ((size_t)(ks * 2 + pp) * BATCH + row) * H1 + n4);
  const f32x4 bv = *(const f32x4*)(ftb + n4);
  s += bv;
  s.x = fminf(fmaxf(s.x, 0.f), 1.f);
  s.y = fminf(fmaxf(s.y, 0.f), 1.f);
  s.z = fminf(fmaxf(s.z, 0.f), 1.f);
  s.w = fminf(fmaxf(s.w, 0.f), 1.f);

  u32x2 o;
  o.x = bfpack2(s.x, s.y);
  o.y = bfpack2(s.z, s.w);
  *(u32x2*)(comb + (size_t)row * 1024 + pp * H1 + n4) = o;
}

// ---------------------------------------------------------------------------
// Kernel 3: fc1 (bf16 MFMA) + relu + fc2 dot + bias -> out FLOAT32 [4096]
// ---------------------------------------------------------------------------
__global__ __launch_bounds__(256)
void fc_kernel(const unsigned short* __restrict__ comb,
               const float* __restrict__ w1, const float* __restrict__ b1,
               const float* __restrict__ w2, const float* __restrict__ b2,
               float* __restrict__ out) {
  __shared__ char smem[40960];  // 2 x (A 4KB + W 16KB)
  __shared__ float rowsum[64];

  const int tid = threadIdx.x;
  const int bm  = blockIdx.x;  // 64 blocks of 64 rows
  if (tid < 64) rowsum[tid] = 0.f;

  const int a_row = tid >> 2, a_kq = tid & 3;
  const unsigned short* aptr = comb + (size_t)(bm * 64 + a_row) * 1024 + a_kq * 8;
  const float* wptr = w1 + (size_t)a_row * 1024 + a_kq * 8;

  u32x4 raA;
  f32x4 rw0[4], rw1[4];
  auto issue = [&](int t) {
    raA = *(const u32x4*)(aptr + t * 32);
    const float* wp = wptr + t * 32;
#pragma unroll
    for (int s = 0; s < 4; ++s) {
      rw0[s] = *(const f32x4*)(wp + (size_t)s * 64 * 1024);
      rw1[s] = *(const f32x4*)(wp + (size_t)s * 64 * 1024 + 4);
    }
  };

  const int aoff_w = lds_swz(a_row, a_kq * 16);
  int woff_w[4];
#pragma unroll
  for (int s = 0; s < 4; ++s)
    woff_w[s] = 4096 + lds_swz(s * 64 + a_row, a_kq * 16);

  auto cvtwrite = [&](int b) {
    char* base = smem + b * 20480;
    *(u32x4*)(base + aoff_w) = raA;
#pragma unroll
    for (int s = 0; s < 4; ++s) {
      u32x4 wv;
      wv.x = bfpack2(rw0[s].x, rw0[s].y); wv.y = bfpack2(rw0[s].z, rw0[s].w);
      wv.z = bfpack2(rw1[s].x, rw1[s].y); wv.w = bfpack2(rw1[s].z, rw1[s].w);
      *(u32x4*)(base + woff_w[s]) = wv;
    }
  };

  const int lane = tid & 63, wn = tid >> 6;
  const int lrow = lane & 15, lkb = (lane >> 4) * 16;
  int a_off[4], b_off[4];
#pragma unroll
  for (int m = 0; m < 4; ++m) a_off[m] = lds_swz(m * 16 + lrow, lkb);
#pragma unroll
  for (int n = 0; n < 4; ++n) b_off[n] = 4096 + lds_swz(wn * 64 + n * 16 + lrow, lkb);

  f32x4 acc[4][4];
#pragma unroll
  for (int m = 0; m < 4; ++m)
#pragma unroll
    for (int n = 0; n < 4; ++n) acc[m][n] = (f32x4){0.f, 0.f, 0.f, 0.f};

  issue(0);
  for (int t = 0; t < 32; ++t) {
    const int b = t & 1;
    cvtwrite(b);
    if (t + 1 < 32) issue(t + 1);
    asm volatile("s_waitcnt lgkmcnt(0)" ::: "memory");
    __builtin_amdgcn_sched_barrier(0);
    __builtin_amdgcn_s_barrier();
    __builtin_amdgcn_sched_barrier(0);
    char* base = smem + b * 20480;
    s16x8 af[4];
#pragma unroll
    for (int m = 0; m < 4; ++m) af[m] = *(const s16x8*)(base + a_off[m]);
#pragma unroll
    for (int n = 0; n < 4; ++n) {
      s16x8 bfn = *(const s16x8*)(base + b_off[n]);
#pragma unroll
      for (int m = 0; m < 4; ++m)
        acc[m][n] = __builtin_amdgcn_mfma_f32_16x16x32_bf16(af[m], bfn, acc[m][n], 0, 0, 0);
    }
  }

  float b1v[4], w2v[4];
#pragma unroll
  for (int n = 0; n < 4; ++n) {
    const int col = wn * 64 + n * 16 + lrow;
    b1v[n] = b1[col];
    w2v[n] = w2[col];
  }
#pragma unroll
  for (int m = 0; m < 4; ++m)
#pragma unroll
    for (int j = 0; j < 4; ++j) {
      float v = 0.f;
#pragma unroll
      for (int n = 0; n < 4; ++n) {
        float x = acc[m][n][j] + b1v[n];
        x = fmaxf(x, 0.f);
        v += x * w2v[n];
      }
#pragma unroll
      for (int d = 1; d < 16; d <<= 1) v += __shfl_xor(v, d, 64);
      if ((lane & 15) == 0)
        atomicAdd(&rowsum[m * 16 + (lane >> 4) * 4 + j], v);
    }
  __syncthreads();
  if (tid < 64) {
    out[bm * 64 + tid] = rowsum[tid] + b2[0];  // f32 output
  }
}

// ---------------------------------------------------------------------------
extern "C" void kernel_launch(void* const* d_in, const int* in_sizes, int n_in,
                              void* d_out, int out_size, void* d_ws, size_t ws_size,
                              hipStream_t stream) {
  const float* whiteF = (const float*)d_in[0];
  const float* blackF = (const float*)d_in[1];
  const float* ftw    = (const float*)d_in[2];
  const float* ftb    = (const float*)d_in[3];
  const float* w1     = (const float*)d_in[4];
  const float* b1     = (const float*)d_in[5];
  const float* w2     = (const float*)d_in[6];
  const float* b2     = (const float*)d_in[7];

  char* wbf = (char*)d_ws;                                   // 41,943,040 B
  const size_t wbf_bytes   = (size_t)NTILES * WTILE;
  const size_t ppart_bytes = (size_t)KS * 2 * BATCH * H1 * sizeof(float);
  float* Ppart = (float*)((char*)d_ws + wbf_bytes);
  unsigned short* comb = (unsigned short*)((char*)d_ws + wbf_bytes + ppart_bytes);
  float* outp = (float*)d_out;

  hipLaunchKernelGGL(wcvt_kernel, dim3(NTILES), dim3(512), 0, stream, ftw, wbf);
  hipLaunchKernelGGL(ft_gemm_kernel, dim3(512), dim3(512), 0, stream,
                     whiteF, blackF, wbf, Ppart);
  hipLaunchKernelGGL(ft_reduce_kernel, dim3((2 * BATCH * H1 / 4) / 256), dim3(256),
                     0, stream, Ppart, ftb, comb);
  hipLaunchKernelGGL(fc_kernel, dim3(BATCH / 64), dim3(256), 0, stream,
                     comb, w1, b1, w2, b2, outp);
}

// Round 9
// 541.622 us; speedup vs baseline: 2.7002x; 1.0222x over previous
//
#include <hip/hip_runtime.h>
#include <stdint.h>

#define BATCH 4096
#define FEAT  40960
#define H1    512
#define KS    4
#define KCHUNK (FEAT / KS)    // 10240
#define NSTEPS (KCHUNK / 32)  // 320
#define NTILES (FEAT / 32)    // 1280
#define WTILE  32768          // bytes per fragment-major W k-tile
#define WSLOT  32768          // LDS W ring slot (8 waves x 4KB)
#define ALDS   65536          // A ring base: 2 x 4KB @ 65536, 69632

typedef float f32x4 __attribute__((ext_vector_type(4)));
typedef short s16x8 __attribute__((ext_vector_type(8)));
typedef unsigned int u32x2 __attribute__((ext_vector_type(2)));
typedef unsigned int u32x4 __attribute__((ext_vector_type(4)));

// round-to-nearest-even f32 -> bf16, packed pair (lo in low 16 bits)
__device__ __forceinline__ unsigned bfpack2(float lo, float hi) {
  unsigned a = __float_as_uint(lo);
  unsigned b = __float_as_uint(hi);
  a += 0x7FFFu + ((a >> 16) & 1u);
  b += 0x7FFFu + ((b >> 16) & 1u);
  return (a >> 16) | (b & 0xFFFF0000u);
}

// Swizzle for 64B-row LDS tiles (A staging), 16B granularity; 2-way = free.
__device__ __forceinline__ int lds_swz(int r, int cb) {
  return (r << 6) + (cb ^ (((r >> 1) & 3) << 4));
}

// async global->LDS, 16B per lane; LDS dest = wave-uniform base + lane*16.
__device__ __forceinline__ void glds16(const void* g, void* l) {
  __builtin_amdgcn_global_load_lds(
      (const __attribute__((address_space(1))) unsigned*)g,
      (__attribute__((address_space(3))) unsigned*)l, 16, 0, 0);
}

// ---------------------------------------------------------------------------
// Kernel 0: one-time ftw f32 -> bf16 in FRAGMENT-MAJOR order:
// wbf[T][nb][f][lane][8 bf16] — a wave's B-fragment is one contiguous 1KB.
// ---------------------------------------------------------------------------
__global__ __launch_bounds__(512)
void wcvt_kernel(const float* __restrict__ ftw, char* __restrict__ wbf) {
  const int T = blockIdx.x;  // 0..NTILES-1
  const int tid = threadIdx.x;
  const int c  = tid & 7;
  const int r0 = tid >> 3;
#pragma unroll
  for (int pass = 0; pass < 8; ++pass) {
    const int r = pass * 64 + r0;
    const float* src = ftw + (size_t)r * FEAT + T * 32 + c * 4;
    f32x4 v = *(const f32x4*)src;
    u32x2 o;
    o.x = bfpack2(v.x, v.y);
    o.y = bfpack2(v.z, v.w);
    const int nb = r >> 6, f = (r >> 4) & 3, lr = r & 15;
    const int l = (c >> 1) * 16 + lr;
    *(u32x2*)(wbf + (size_t)T * WTILE + ((nb * 4 + f) << 10) + l * 16 +
              (c & 1) * 8) = o;
  }
}

// ---------------------------------------------------------------------------
// Kernel 1: feature-transform GEMM, split-K partials. DEPTH-2 PIPELINE.
// BM=64 BN=512 BK=32, 512 thr = 8 waves (1M x 8N), wave tile 64x64.
// W: per-wave-disjoint LDS ring (2 x 4KB/wave), DMA'd 2 steps ahead via
//    global_load_lds; consumed by same wave -> counted vmcnt, never drained.
// A: f32 reg-loaded 2 steps ahead (raA[2]), cvt'd+staged to 2-slot LDS ring
//    1 step ahead; the single per-step raw barrier covers only A visibility
//    (lgkm-only). Per-wave vm queue at step top = [W(t):4, A(t+1):1,
//    W(t+1):4, A(t+2):1] = 10 -> vmcnt(5) completes W(t)+A(t+1), keeps 5 in
//    flight across the barrier. Tail uses clamped dummy loads (uniform cnt);
//    a final vmcnt(0) drain before the epilogue prevents in-flight LDS DMA
//    at s_endpgm (LDS could be reallocated to a new block -> corruption).
// LDS 72KB, regs ~56 VGPR + 64 AGPR -> 2 blocks/CU, 16 waves/CU.
// ---------------------------------------------------------------------------
__global__ __launch_bounds__(512, 4)
void ft_gemm_kernel(const float* __restrict__ whiteF,
                    const float* __restrict__ blackF,
                    const char* __restrict__ wbf,
                    float* __restrict__ Ppart) {
  __shared__ char smem[73728];  // W slots @0,32768 | A slots @65536,69632

  const int tid = threadIdx.x, bid = blockIdx.x;
  const int wgid = (bid & 7) * 64 + (bid >> 3);  // XCD-chunked, bijective
  const int ks = wgid >> 7;
  const int p  = (wgid >> 6) & 1;
  const int mt = wgid & 63;

  const float* Ag =
      (p == 0 ? whiteF : blackF) + (size_t)(mt * 64) * FEAT + ks * KCHUNK;

  // A staging: 64 rows x 8 threads/row x 4 f32 (row chunks of 128B)
  const int a_row = tid >> 3, a_kc = tid & 7;
  const float* aptr = Ag + (size_t)a_row * FEAT + a_kc * 4;
  const int awoff = lds_swz(a_row, a_kc * 8);  // + ALDS + slot*4096

  const int lane = tid & 63, wave = tid >> 6;
  const int lrow = lane & 15, lkb = (lane >> 4) * 16;

  const char* wsrc =
      wbf + (size_t)ks * NSTEPS * WTILE + (wave << 12) + lane * 16;
  const int wofs = (wave << 12);  // + slot*WSLOT; frag n at +n*1024+lane*16

  int a_off[4];
#pragma unroll
  for (int m = 0; m < 4; ++m) a_off[m] = lds_swz(m * 16 + lrow, lkb);

  f32x4 acc[4][4];
#pragma unroll
  for (int m = 0; m < 4; ++m)
#pragma unroll
    for (int n = 0; n < 4; ++n) acc[m][n] = (f32x4){0.f, 0.f, 0.f, 0.f};

  f32x4 raA[2];  // raA[s] holds A(t) f32 with t%2==s, loaded 2 steps ahead

  // ---- prologue: queue becomes [A0, A1, W0x4, W1x4]; drain A0; stage it.
  raA[0] = *(const f32x4*)aptr;
  raA[1] = *(const f32x4*)(aptr + 32);
#pragma unroll
  for (int c = 0; c < 4; ++c)
    glds16(wsrc + c * 1024, smem + 0 * WSLOT + wofs + c * 1024);
#pragma unroll
  for (int c = 0; c < 4; ++c)
    glds16(wsrc + WTILE + c * 1024, smem + 1 * WSLOT + wofs + c * 1024);
  asm volatile("s_waitcnt vmcnt(9)" ::: "memory");  // A0 done
  __builtin_amdgcn_sched_barrier(0);
  {
    u32x2 av;
    av.x = bfpack2(raA[0].x, raA[0].y);
    av.y = bfpack2(raA[0].z, raA[0].w);
    *(u32x2*)(smem + ALDS + 0 * 4096 + awoff) = av;
  }
  raA[0] = *(const f32x4*)(aptr + 2 * 32);  // A2
  asm volatile("s_waitcnt lgkmcnt(0)" ::: "memory");
  __builtin_amdgcn_sched_barrier(0);
  __builtin_amdgcn_s_barrier();
  __builtin_amdgcn_sched_barrier(0);
  // steady-state queue: [A1, W0x4, W1x4, A2] = 10

#define GSTEP(B, t)                                                           \
  {                                                                           \
    asm volatile("s_waitcnt vmcnt(5)" ::: "memory"); /* W(t), A(t+1) done */  \
    __builtin_amdgcn_sched_barrier(0);                                        \
    const char* wbase = smem + (B) * WSLOT + wofs;                            \
    const char* abase = smem + ALDS + (B) * 4096;                             \
    s16x8 af[4], wb[4];                                                       \
    _Pragma("unroll") for (int m = 0; m < 4; ++m)                             \
        af[m] = *(const s16x8*)(abase + a_off[m]);                            \
    _Pragma("unroll") for (int n = 0; n < 4; ++n)                             \
        wb[n] = *(const s16x8*)(wbase + n * 1024 + lane * 16);                \
    asm volatile("s_waitcnt lgkmcnt(0)" ::: "memory"); /* reads landed */     \
    __builtin_amdgcn_sched_barrier(0);                                        \
    { /* W(t+2) DMA into slot (t+2)%2 == B (just-freed) */                    \
      const int t2 = ((t) + 2 < NSTEPS) ? (t) + 2 : NSTEPS - 1;               \
      const char* wsp = wsrc + (size_t)t2 * WTILE;                            \
      char* wdp = smem + (B) * WSLOT + wofs;                                  \
      _Pragma("unroll") for (int c = 0; c < 4; ++c)                           \
          glds16(wsp + c * 1024, wdp + c * 1024);                             \
    }                                                                         \
    { /* cvt+stage A(t+1) -> A slot B^1; reload raA[B^1] with A(t+3) */       \
      u32x2 av;                                                               \
      av.x = bfpack2(raA[(B) ^ 1].x, raA[(B) ^ 1].y);                         \
      av.y = bfpack2(raA[(B) ^ 1].z, raA[(B) ^ 1].w);                         \
      *(u32x2*)(smem + ALDS + ((B) ^ 1) * 4096 + awoff) = av;                 \
      const int t3 = ((t) + 3 < NSTEPS) ? (t) + 3 : NSTEPS - 1;               \
      raA[(B) ^ 1] = *(const f32x4*)(aptr + (size_t)t3 * 32);                 \
    }                                                                         \
    _Pragma("unroll") for (int n = 0; n < 4; ++n)                             \
      _Pragma("unroll") for (int m = 0; m < 4; ++m)                           \
          acc[m][n] = __builtin_amdgcn_mfma_f32_16x16x32_bf16(                \
              af[m], wb[n], acc[m][n], 0, 0, 0);                              \
    asm volatile("s_waitcnt lgkmcnt(0)" ::: "memory"); /* A-write visible */  \
    __builtin_amdgcn_sched_barrier(0);                                        \
    __builtin_amdgcn_s_barrier();                                             \
    __builtin_amdgcn_sched_barrier(0);                                        \
  }

  for (int tt = 0; tt < NSTEPS; tt += 2) {
    GSTEP(0, tt);
    GSTEP(1, tt + 1);
  }
#undef GSTEP

  // Drain all in-flight DMA/loads before epilogue: a wave must not reach
  // s_endpgm with outstanding LDS-targeting DMA (LDS may be reallocated).
  asm volatile("s_waitcnt vmcnt(0) lgkmcnt(0)" ::: "memory");
  __builtin_amdgcn_sched_barrier(0);

  // C/D frag: col = lane&15, row = (lane>>4)*4 + j
  float* Pp = Ppart + ((size_t)(ks * 2 + p) * BATCH + mt * 64) * H1;
  const int r0 = (lane >> 4) * 4;
  const int c0 = wave * 64 + lrow;
#pragma unroll
  for (int m = 0; m < 4; ++m)
#pragma unroll
    for (int n = 0; n < 4; ++n) {
      float* dst = Pp + (size_t)(r0 + m * 16) * H1 + c0 + n * 16;
#pragma unroll
      for (int j = 0; j < 4; ++j) dst[(size_t)j * H1] = acc[m][n][j];
    }
}

// ---------------------------------------------------------------------------
// Kernel 2: reduce split-K partials + bias + clip[0,1] -> combined bf16
// ---------------------------------------------------------------------------
__global__ __launch_bounds__(256)
void ft_reduce_kernel(const float* __restrict__ Ppart,
                      const float* __restrict__ ftb,
                      unsigned short* __restrict__ comb) {
  const size_t gid = (size_t)blockIdx.x * 256 + threadIdx.x;  // 2*B*H1/4
  const int    pp  = (int)(gid / (BATCH * H1 / 4));
  const size_t rem = gid % (BATCH * H1 / 4);
  const int    row = (int)(rem / (H1 / 4));
  const int    n4  = (int)(rem % (H1 / 4)) * 4;

  f32x4 s = (f32x4){0.f, 0.f, 0.f, 0.f};
#pragma unroll
  for (int ks = 0; ks < KS; ++ks)
    s += *(const f32x4*)(Ppart + ((size_t)(ks * 2 + pp) * BATCH + row) * H1 + n4);
  const f32x4 bv = *(const f32x4*)(ftb + n4);
  s += bv;
  s.x = fminf(fmaxf(s.x, 0.f), 1.f);
  s.y = fminf(fmaxf(s.y, 0.f), 1.f);
  s.z = fminf(fmaxf(s.z, 0.f), 1.f);
  s.w = fminf(fmaxf(s.w, 0.f), 1.f);

  u32x2 o;
  o.x = bfpack2(s.x, s.y);
  o.y = bfpack2(s.z, s.w);
  *(u32x2*)(comb + (size_t)row * 1024 + pp * H1 + n4) = o;
}

// ---------------------------------------------------------------------------
// Kernel 3: fc1 (bf16 MFMA) + relu + fc2 dot + bias -> out FLOAT32 [4096]
// ---------------------------------------------------------------------------
__global__ __launch_bounds__(256)
void fc_kernel(const unsigned short* __restrict__ comb,
               const float* __restrict__ w1, const float* __restrict__ b1,
               const float* __restrict__ w2, const float* __restrict__ b2,
               float* __restrict__ out) {
  __shared__ char smem[40960];  // 2 x (A 4KB + W 16KB)
  __shared__ float rowsum[64];

  const int tid = threadIdx.x;
  const int bm  = blockIdx.x;  // 64 blocks of 64 rows
  if (tid < 64) rowsum[tid] = 0.f;

  const int a_row = tid >> 2, a_kq = tid & 3;
  const unsigned short* aptr = comb + (size_t)(bm * 64 + a_row) * 1024 + a_kq * 8;
  const float* wptr = w1 + (size_t)a_row * 1024 + a_kq * 8;

  u32x4 raA;
  f32x4 rw0[4], rw1[4];
  auto issue = [&](int t) {
    raA = *(const u32x4*)(aptr + t * 32);
    const float* wp = wptr + t * 32;
#pragma unroll
    for (int s = 0; s < 4; ++s) {
      rw0[s] = *(const f32x4*)(wp + (size_t)s * 64 * 1024);
      rw1[s] = *(const f32x4*)(wp + (size_t)s * 64 * 1024 + 4);
    }
  };

  const int aoff_w = lds_swz(a_row, a_kq * 16);
  int woff_w[4];
#pragma unroll
  for (int s = 0; s < 4; ++s)
    woff_w[s] = 4096 + lds_swz(s * 64 + a_row, a_kq * 16);

  auto cvtwrite = [&](int b) {
    char* base = smem + b * 20480;
    *(u32x4*)(base + aoff_w) = raA;
#pragma unroll
    for (int s = 0; s < 4; ++s) {
      u32x4 wv;
      wv.x = bfpack2(rw0[s].x, rw0[s].y); wv.y = bfpack2(rw0[s].z, rw0[s].w);
      wv.z = bfpack2(rw1[s].x, rw1[s].y); wv.w = bfpack2(rw1[s].z, rw1[s].w);
      *(u32x4*)(base + woff_w[s]) = wv;
    }
  };

  const int lane = tid & 63, wn = tid >> 6;
  const int lrow = lane & 15, lkb = (lane >> 4) * 16;
  int a_off[4], b_off[4];
#pragma unroll
  for (int m = 0; m < 4; ++m) a_off[m] = lds_swz(m * 16 + lrow, lkb);
#pragma unroll
  for (int n = 0; n < 4; ++n) b_off[n] = 4096 + lds_swz(wn * 64 + n * 16 + lrow, lkb);

  f32x4 acc[4][4];
#pragma unroll
  for (int m = 0; m < 4; ++m)
#pragma unroll
    for (int n = 0; n < 4; ++n) acc[m][n] = (f32x4){0.f, 0.f, 0.f, 0.f};

  issue(0);
  for (int t = 0; t < 32; ++t) {
    const int b = t & 1;
    cvtwrite(b);
    if (t + 1 < 32) issue(t + 1);
    asm volatile("s_waitcnt lgkmcnt(0)" ::: "memory");
    __builtin_amdgcn_sched_barrier(0);
    __builtin_amdgcn_s_barrier();
    __builtin_amdgcn_sched_barrier(0);
    char* base = smem + b * 20480;
    s16x8 af[4];
#pragma unroll
    for (int m = 0; m < 4; ++m) af[m] = *(const s16x8*)(base + a_off[m]);
#pragma unroll
    for (int n = 0; n < 4; ++n) {
      s16x8 bfn = *(const s16x8*)(base + b_off[n]);
#pragma unroll
      for (int m = 0; m < 4; ++m)
        acc[m][n] = __builtin_amdgcn_mfma_f32_16x16x32_bf16(af[m], bfn, acc[m][n], 0, 0, 0);
    }
  }

  float b1v[4], w2v[4];
#pragma unroll
  for (int n = 0; n < 4; ++n) {
    const int col = wn * 64 + n * 16 + lrow;
    b1v[n] = b1[col];
    w2v[n] = w2[col];
  }
#pragma unroll
  for (int m = 0; m < 4; ++m)
#pragma unroll
    for (int j = 0; j < 4; ++j) {
      float v = 0.f;
#pragma unroll
      for (int n = 0; n < 4; ++n) {
        float x = acc[m][n][j] + b1v[n];
        x = fmaxf(x, 0.f);
        v += x * w2v[n];
      }
#pragma unroll
      for (int d = 1; d < 16; d <<= 1) v += __shfl_xor(v, d, 64);
      if ((lane & 15) == 0)
        atomicAdd(&rowsum[m * 16 + (lane >> 4) * 4 + j], v);
    }
  __syncthreads();
  if (tid < 64) {
    out[bm * 64 + tid] = rowsum[tid] + b2[0];  // f32 output
  }
}

// ---------------------------------------------------------------------------
extern "C" void kernel_launch(void* const* d_in, const int* in_sizes, int n_in,
                              void* d_out, int out_size, void* d_ws, size_t ws_size,
                              hipStream_t stream) {
  const float* whiteF = (const float*)d_in[0];
  const float* blackF = (const float*)d_in[1];
  const float* ftw    = (const float*)d_in[2];
  const float* ftb    = (const float*)d_in[3];
  const float* w1     = (const float*)d_in[4];
  const float* b1     = (const float*)d_in[5];
  const float* w2     = (const float*)d_in[6];
  const float* b2     = (const float*)d_in[7];

  char* wbf = (char*)d_ws;                                   // 41,943,040 B
  const size_t wbf_bytes   = (size_t)NTILES * WTILE;
  const size_t ppart_bytes = (size_t)KS * 2 * BATCH * H1 * sizeof(float);
  float* Ppart = (float*)((char*)d_ws + wbf_bytes);
  unsigned short* comb = (unsigned short*)((char*)d_ws + wbf_bytes + ppart_bytes);
  float* outp = (float*)d_out;

  hipLaunchKernelGGL(wcvt_kernel, dim3(NTILES), dim3(512), 0, stream, ftw, wbf);
  hipLaunchKernelGGL(ft_gemm_kernel, dim3(512), dim3(512), 0, stream,
                     whiteF, blackF, wbf, Ppart);
  hipLaunchKernelGGL(ft_reduce_kernel, dim3((2 * BATCH * H1 / 4) / 256), dim3(256),
                     0, stream, Ppart, ftb, comb);
  hipLaunchKernelGGL(fc_kernel, dim3(BATCH / 64), dim3(256), 0, stream,
                     comb, w1, b1, w2, b2, outp);
}